// Round 5
// baseline (198.580 us; speedup 1.0000x reference)
//
#include <hip/hip_runtime.h>
#include <hip/hip_bf16.h>
#include <math.h>
#include <float.h>

// b=8, c=64, H=W=64, KS=8 -> P = 57*57 = 3249.
// Stage 1 per (b,c): G[m,n] = <patch_m, patch_n> over P; corr = G/(sqrt(diag)sqrt(diag)P);
//   sort 64 m per column n desc; ranks {1,9,16,24,32,40,48,55,63} -> xp[b,c,576].
// Stage 2 per b: corr2[p,q] = sum_c Xn[c,p]Xn[c,q]/64; sort 576 p per q desc; 115 ranks.
//
// Stage-1 shift set: dj in 0..7; di in -7..7 with (dj==0 -> di>=0). Mirror-stored.

#define IMGS 65
__device__ __constant__ int WOFF[8] = {0, 8, 15, 21, 26, 30, 33, 35};  // 36 packed (dj,st)

// ---------------- k1a: Gram via row-window FMA + lane prefix-scan (no Wb LDS) ----------
// grid = 512*4 (bc x quad), block = 256; wave wv handles di = quad*4 + wv - 7 (skip 8)
__global__ __launch_bounds__(256) void k1a(const float* __restrict__ x,
                                           float* __restrict__ Gg) {
    __shared__ float img[64 * IMGS];   // 16.6 KB, stride 65 -> 2-way max (free)

    const int t = threadIdx.x;
    const int bc = blockIdx.x >> 2, qd = blockIdx.x & 3;
    const float* src = x + (size_t)bc * 4096;

    #pragma unroll
    for (int k = 0; k < 4; ++k) {
        int i4 = t + k * 256;
        float4 v = ((const float4*)src)[i4];
        int fl = i4 * 4, row = fl >> 6, col = fl & 63;
        float* d = &img[row * IMGS + col];
        d[0] = v.x; d[1] = v.y; d[2] = v.z; d[3] = v.w;
    }
    __syncthreads();

    const int wv = t >> 6, lane = t & 63;
    const int di = qd * 4 + wv - 7;            // -7..8
    if (di > 7) return;                        // wave 15 invalid (no barriers follow)

    const int a = lane;
    const int alo = di < 0 ? -di : 0, ahi = di > 0 ? 63 - di : 63;
    const bool av = (a >= alo && a <= ahi);
    const int a1 = min(max(a + di, 0), 63);    // clamped partner row (garbage if !av)
    const float* r0 = &img[a * IMGS];
    const float* r1 = &img[a1 * IMGS];

    // ---- row-window sums w[dj] = sum_{u=0..56} r0[u]*r1[u+dj], circular shift reg ----
    float w[8] = {0, 0, 0, 0, 0, 0, 0, 0};
    float s[8];
    #pragma unroll
    for (int k = 0; k < 7; ++k) s[k] = r1[k];
    #pragma unroll
    for (int c = 0; c < 7; ++c) {
        #pragma unroll
        for (int j = 0; j < 8; ++j) {
            const int u = c * 8 + j;
            s[(j + 7) & 7] = r1[u + 7];
            const float r0u = r0[u];
            #pragma unroll
            for (int k = 0; k < 8; ++k) w[k] = fmaf(r0u, s[(j + k) & 7], w[k]);
        }
    }
    {   // u = 56 (j pattern wraps to 0)
        s[7] = r1[63];
        const float r0u = r0[56];
        #pragma unroll
        for (int k = 0; k < 8; ++k) w[k] = fmaf(r0u, s[k], w[k]);
    }

    // ---- slide over st: W[dj][st], st < 8-dj, packed into 36 registers ----
    float r0h[7], r0t[7], r1t[7], r1h[7];
    #pragma unroll
    for (int k = 0; k < 7; ++k) {
        r0h[k] = r0[k];      r0t[k] = r0[57 + k];
        r1h[k] = r1[k];      r1t[k] = r1[57 + k];
    }
    float W[36];
    #pragma unroll
    for (int dj = 0; dj < 8; ++dj) {
        float ww = w[dj];
        W[WOFF[dj]] = ww;
        #pragma unroll
        for (int st = 1; st < 8 - dj; ++st) {
            ww += r0t[st - 1] * r1t[st - 1 + dj] - r0h[st - 1] * r1h[st - 1 + dj];
            W[WOFF[dj] + st] = ww;
        }
    }
    const float msk = av ? 1.0f : 0.0f;
    #pragma unroll
    for (int i = 0; i < 36; ++i) W[i] *= msk;

    // ---- inclusive prefix scan over lanes (rows) for all 36 values ----
    #pragma unroll
    for (int sp = 1; sp < 64; sp <<= 1) {
        #pragma unroll
        for (int i = 0; i < 36; ++i) {
            float o = __shfl_up(W[i], sp, 64);
            W[i] += (lane >= sp) ? o : 0.0f;
        }
    }

    // ---- extract column windows: S(ki) = P[ki+56] - P[ki-1]; write G + mirror ----
    const int kilo = di < 0 ? -di : 0;
    const int kihi = di > 0 ? 7 - di : 7;
    const int nki = kihi - kilo + 1;
    const int ki = kilo + lane;
    const int srcU = (kilo + lane + 56) & 63;
    const int srcL = (kilo + lane - 1) & 63;
    const bool wr = lane < nki;
    float* g = Gg + (size_t)bc * 4096;
    #pragma unroll
    for (int dj = 0; dj < 8; ++dj) {
        if (di < 0 && dj == 0) continue;       // mirror of (di>0, dj=0)
        #pragma unroll
        for (int st = 0; st < 8 - dj; ++st) {
            const float Pv = W[WOFF[dj] + st];
            const float su = __shfl(Pv, srcU, 64);
            const float sl = __shfl(Pv, srcL, 64);
            if (wr) {
                const float S = su - ((ki > 0) ? sl : 0.0f);
                const int m = ki * 8 + st, n = (ki + di) * 8 + (st + dj);
                g[m * 64 + n] = S;
                g[n * 64 + m] = S;
            }
        }
    }
}

// ---------------- k1b: normalize + cross-lane sort64 + ranked pool -> xp ----------------
// grid = 512*4, block = 256 (4 waves x 4 columns each), no LDS / no barriers
__global__ __launch_bounds__(256) void k1b(const float* __restrict__ Gg,
                                           float* __restrict__ xp) {
    const int t = threadIdx.x;
    const int bc = blockIdx.x >> 2, seg = blockIdx.x & 3;
    const int wv = t >> 6, lane = t & 63;
    const int n0 = seg * 16 + wv * 4;
    const float* g = Gg + (size_t)bc * 4096;
    float invm = 1.0f / fmaxf(sqrtf(g[lane * 65]), 1e-12f);   // diag gather (L2)
    const float sc = 1.0f / 3249.0f;
    float v[4];
    #pragma unroll
    for (int c = 0; c < 4; ++c) {
        float bn = __shfl(invm, n0 + c, 64);
        v[c] = g[(n0 + c) * 64 + lane] * invm * bn * sc;   // symmetric: row read coalesced
    }
    #pragma unroll
    for (int kk = 2; kk <= 64; kk <<= 1) {
        #pragma unroll
        for (int j = kk >> 1; j > 0; j >>= 1) {
            bool upper = (lane & j) != 0;
            bool dir0  = (lane & kk) == 0;
            bool keep_max = dir0 ^ upper;
            float o[4];
            #pragma unroll
            for (int c = 0; c < 4; ++c) o[c] = __shfl_xor(v[c], j, 64);
            #pragma unroll
            for (int c = 0; c < 4; ++c) v[c] = keep_max ? fmaxf(v[c], o[c]) : fminf(v[c], o[c]);
        }
    }
    int ridx = -1;
    if      (lane ==  1) ridx = 0; else if (lane ==  9) ridx = 1; else if (lane == 16) ridx = 2;
    else if (lane == 24) ridx = 3; else if (lane == 32) ridx = 4; else if (lane == 40) ridx = 5;
    else if (lane == 48) ridx = 6; else if (lane == 55) ridx = 7; else if (lane == 63) ridx = 8;
    if (ridx >= 0) {
        #pragma unroll
        for (int c = 0; c < 4; ++c)
            xp[(size_t)bc * 576 + ridx * 64 + n0 + c] = v[c];
    }
}

// ---------------- k3a: stage-2 Gram, LDS-tiled GEMM 64x64 tiles, fused norms ----------
// grid = 8*81 (b x 9x9 tiles), block = 256, 4x4 acc/thread; writes 576-wide rows
__global__ __launch_bounds__(256) void k3a(const float* __restrict__ xp,
                                           float* __restrict__ c2) {
    __shared__ __align__(16) float As[64 * 68];
    __shared__ __align__(16) float Bs[64 * 68];
    __shared__ __align__(16) float ipv[64], iqv[64];
    const int t = threadIdx.x;
    const int b = blockIdx.x / 81;
    const int r = blockIdx.x % 81;
    const int pt = r / 9, qt = r % 9;
    const int p0 = pt * 64, q0 = qt * 64;
    const float4* xp4 = (const float4*)(xp + (size_t)b * 64 * 576);

    #pragma unroll
    for (int k = 0; k < 4; ++k) {
        int c = k * 16 + (t >> 4), j = t & 15;
        *(float4*)&As[c * 68 + j * 4] = xp4[c * 144 + (p0 >> 2) + j];
        *(float4*)&Bs[c * 68 + j * 4] = xp4[c * 144 + (q0 >> 2) + j];
    }
    __syncthreads();

    if (t < 64) {
        float s = 0.f;
        #pragma unroll
        for (int c = 0; c < 64; ++c) { float vv = As[c * 68 + t]; s = fmaf(vv, vv, s); }
        ipv[t] = 1.0f / fmaxf(sqrtf(s), 1e-12f);
    } else if (t < 128) {
        int u = t - 64; float s = 0.f;
        #pragma unroll
        for (int c = 0; c < 64; ++c) { float vv = Bs[c * 68 + u]; s = fmaf(vv, vv, s); }
        iqv[u] = 1.0f / fmaxf(sqrtf(s), 1e-12f);
    }
    __syncthreads();

    const int tp = t & 15, tq = t >> 4;
    float acc[4][4] = {};
    #pragma unroll
    for (int c = 0; c < 64; ++c) {
        float4 a4 = *(const float4*)&As[c * 68 + tp * 4];
        float4 b4 = *(const float4*)&Bs[c * 68 + tq * 4];
        acc[0][0] = fmaf(a4.x, b4.x, acc[0][0]); acc[0][1] = fmaf(a4.x, b4.y, acc[0][1]);
        acc[0][2] = fmaf(a4.x, b4.z, acc[0][2]); acc[0][3] = fmaf(a4.x, b4.w, acc[0][3]);
        acc[1][0] = fmaf(a4.y, b4.x, acc[1][0]); acc[1][1] = fmaf(a4.y, b4.y, acc[1][1]);
        acc[1][2] = fmaf(a4.y, b4.z, acc[1][2]); acc[1][3] = fmaf(a4.y, b4.w, acc[1][3]);
        acc[2][0] = fmaf(a4.z, b4.x, acc[2][0]); acc[2][1] = fmaf(a4.z, b4.y, acc[2][1]);
        acc[2][2] = fmaf(a4.z, b4.z, acc[2][2]); acc[2][3] = fmaf(a4.z, b4.w, acc[2][3]);
        acc[3][0] = fmaf(a4.w, b4.x, acc[3][0]); acc[3][1] = fmaf(a4.w, b4.y, acc[3][1]);
        acc[3][2] = fmaf(a4.w, b4.z, acc[3][2]); acc[3][3] = fmaf(a4.w, b4.w, acc[3][3]);
    }

    float4 ip4 = *(const float4*)&ipv[tp * 4];
    #pragma unroll
    for (int qq = 0; qq < 4; ++qq) {
        int q = q0 + tq * 4 + qq;
        float iqs = iqv[tq * 4 + qq] * 0.015625f;   // /64
        float4 o;
        o.x = acc[0][qq] * ip4.x * iqs;
        o.y = acc[1][qq] * ip4.y * iqs;
        o.z = acc[2][qq] * ip4.z * iqs;
        o.w = acc[3][qq] * ip4.w * iqs;
        *(float4*)&c2[((size_t)(b * 576 + q)) * 576 + p0 + tp * 4] = o;
    }
}

// ---------------- k3b: per-wave register bitonic sort1024 + ranked scatter ----------------
// grid = 1152 (4 columns per block, one per wave), block = 256, no LDS / no barriers
__global__ __launch_bounds__(256) void k3b(const float* __restrict__ c2,
                                           float* __restrict__ out) {
    const int t = threadIdx.x;
    const int gw = blockIdx.x * 4 + (t >> 6);     // 0..4607 = b*576+q
    const int b = gw / 576, q = gw % 576;
    const int lane = t & 63;
    float v[16];
    if (lane < 36) {                              // 36*16 = 576 real elements
        const float4* row4 = (const float4*)(c2 + (size_t)gw * 576);
        #pragma unroll
        for (int k = 0; k < 4; ++k) {
            float4 f = row4[lane * 4 + k];
            v[k * 4 + 0] = f.x; v[k * 4 + 1] = f.y; v[k * 4 + 2] = f.z; v[k * 4 + 3] = f.w;
        }
    } else {
        #pragma unroll
        for (int r = 0; r < 16; ++r) v[r] = -FLT_MAX;   // virtual padding to 1024
    }

    #pragma unroll
    for (int kk = 2; kk <= 1024; kk <<= 1) {
        #pragma unroll
        for (int j = kk >> 1; j > 0; j >>= 1) {
            if (j >= 16) {
                const int jl = j >> 4;
                bool upper = (lane & jl) != 0;
                bool dir0  = (lane & (kk >> 4)) == 0;
                bool keep_max = dir0 ^ upper;
                float o[16];
                #pragma unroll
                for (int r = 0; r < 16; ++r) o[r] = __shfl_xor(v[r], jl, 64);
                #pragma unroll
                for (int r = 0; r < 16; ++r) v[r] = keep_max ? fmaxf(v[r], o[r]) : fminf(v[r], o[r]);
            } else {
                #pragma unroll
                for (int ra = 0; ra < 16; ++ra) {
                    if ((ra & j) == 0) {
                        const int rb = ra | j;
                        bool dir0 = (kk >= 16) ? ((lane & (kk >> 4)) == 0) : ((ra & kk) == 0);
                        float a = v[ra], bb = v[rb];
                        float mx = fmaxf(a, bb), mn = fminf(a, bb);
                        v[ra] = dir0 ? mx : mn;
                        v[rb] = dir0 ? mn : mx;
                    }
                }
            }
        }
    }

    // ranks = round(linspace(1,575,115)) == 1 + 5i + floor(2i/57) + (2i%57>=29)
    float* ob = out + (size_t)b * 115 * 576 + q;
    #pragma unroll
    for (int r = 0; r < 16; ++r) {
        int pos = lane * 16 + r;
        int rr0 = (int)((float)pos * 0.1993f);
        #pragma unroll
        for (int dd = -1; dd <= 2; ++dd) {
            int cand = rr0 + dd;
            if (cand >= 0 && cand < 115) {
                int ti = 2 * cand;
                int rk = 1 + 5 * cand + ti / 57 + ((ti % 57) >= 29 ? 1 : 0);
                if (rk == pos) ob[(size_t)cand * 576] = v[r];
            }
        }
    }
}

extern "C" void kernel_launch(void* const* d_in, const int* in_sizes, int n_in,
                              void* d_out, int out_size, void* d_ws, size_t ws_size,
                              hipStream_t stream) {
    const float* x = (const float*)d_in[0];   // [8,64,64,64] fp32
    float* out = (float*)d_out;               // [8,115,24,24] fp32
    float* xp = (float*)d_ws;                 // [8,64,576] = 294912 floats
    float* R  = xp + 294912;                  // union (sequential lifetimes):
    float* Gg = R;                            //   [512,4096]  = 2,097,152 floats
    float* c2 = R;                            //   [8,576,576] = 2,654,208 floats
    // ws use: (294912 + 2654208)*4 B ~= 11.8 MiB

    k1a<<<dim3(2048), dim3(256), 0, stream>>>(x, Gg);
    k1b<<<dim3(2048), dim3(256), 0, stream>>>(Gg, xp);
    k3a<<<dim3(648),  dim3(256), 0, stream>>>(xp, c2);
    k3b<<<dim3(1152), dim3(256), 0, stream>>>(c2, out);
}

// Round 6
// 141.200 us; speedup vs baseline: 1.4064x; 1.4064x over previous
//
#include <hip/hip_runtime.h>
#include <hip/hip_bf16.h>
#include <math.h>
#include <float.h>

// b=8, c=64, H=W=64, KS=8 -> P = 57*57 = 3249.
// Stage 1 per (b,c): G[m,n] = <patch_m, patch_n> over P; corr = G/(sqrt(diag)sqrt(diag)P);
//   sort 64 m per column n desc; ranks {1,9,16,24,32,40,48,55,63} -> xp[b,c,576].
// Stage 2 per b: corr2[p,q] = sum_c Xn[c,p]Xn[c,q]/64; sort 576 p per q desc; 115 ranks.
//
// Stage-1 shift set: dj in 0..7; di in -7..7 with (dj==0 -> di>=0). Mirror-stored.

#define IMGS 65

// packed offset of (dj) run in W[36]:  {0,8,15,21,26,30,33,35} — COMPILE-TIME ONLY
// (R5 lesson: a __constant__ array here is a runtime load -> W[] demoted to scratch,
//  VGPR=32 + 181MB spill writes. constexpr keeps every W[] index static.)
__host__ __device__ constexpr int woff(int dj) { return dj * (17 - dj) / 2; }

// ---------------- k1: fused stage-1 (Gram in LDS + normalize + sort64 + pool) ----------
// grid = 512 (one block per bc), block = 256 (4 waves; wave handles 4 di values)
__global__ __launch_bounds__(256) void k1(const float* __restrict__ x,
                                          float* __restrict__ xp) {
    __shared__ float img[64 * IMGS];   // 16.6 KB, stride 65
    __shared__ float G[64 * IMGS];     // 16.6 KB, stride 65 (scattered writes ~2-way)

    const int t = threadIdx.x;
    const int bc = blockIdx.x;
    const float* src = x + (size_t)bc * 4096;

    #pragma unroll
    for (int k = 0; k < 4; ++k) {
        int i4 = t + k * 256;
        float4 v = ((const float4*)src)[i4];
        int fl = i4 * 4, row = fl >> 6, col = fl & 63;
        float* d = &img[row * IMGS + col];
        d[0] = v.x; d[1] = v.y; d[2] = v.z; d[3] = v.w;
    }
    __syncthreads();

    const int wv = t >> 6, lane = t & 63;

    #pragma unroll 1
    for (int rr = 0; rr < 4; ++rr) {
        const int di = rr * 4 + wv - 7;            // -7..8 (8 = idle: wv=3,rr=3)
        if (di <= 7) {
            const int a = lane;
            const int alo = di < 0 ? -di : 0, ahi = di > 0 ? 63 - di : 63;
            const bool av = (a >= alo && a <= ahi);
            const int a1 = min(max(a + di, 0), 63);
            const float* r0 = &img[a * IMGS];
            const float* r1 = &img[a1 * IMGS];

            // row-window sums w[dj] = sum_{u=0..56} r0[u]*r1[u+dj], circular shift reg
            float w[8] = {0, 0, 0, 0, 0, 0, 0, 0};
            float s[8];
            #pragma unroll
            for (int k = 0; k < 7; ++k) s[k] = r1[k];
            #pragma unroll
            for (int c = 0; c < 7; ++c) {
                #pragma unroll
                for (int j = 0; j < 8; ++j) {
                    const int u = c * 8 + j;
                    s[(j + 7) & 7] = r1[u + 7];
                    const float r0u = r0[u];
                    #pragma unroll
                    for (int k = 0; k < 8; ++k) w[k] = fmaf(r0u, s[(j + k) & 7], w[k]);
                }
            }
            {   // u = 56
                s[7] = r1[63];
                const float r0u = r0[56];
                #pragma unroll
                for (int k = 0; k < 8; ++k) w[k] = fmaf(r0u, s[k], w[k]);
            }

            // slide over st -> W[36] (all indices compile-time)
            float r0h[7], r0t[7], r1h[7], r1t[7];
            #pragma unroll
            for (int k = 0; k < 7; ++k) {
                r0h[k] = r0[k]; r0t[k] = r0[57 + k];
                r1h[k] = r1[k]; r1t[k] = r1[57 + k];
            }
            float W[36];
            #pragma unroll
            for (int dj = 0; dj < 8; ++dj) {
                float ww = w[dj];
                W[woff(dj)] = ww;
                #pragma unroll
                for (int st = 1; st < 8 - dj; ++st) {
                    ww += r0t[st - 1] * r1t[st - 1 + dj] - r0h[st - 1] * r1h[st - 1 + dj];
                    W[woff(dj) + st] = ww;
                }
            }
            const float msk = av ? 1.0f : 0.0f;
            #pragma unroll
            for (int i = 0; i < 36; ++i) W[i] *= msk;

            // inclusive lane prefix-scan (rows) for all 36 values
            #pragma unroll
            for (int sp = 1; sp < 64; sp <<= 1) {
                #pragma unroll
                for (int i = 0; i < 36; ++i) {
                    float o = __shfl_up(W[i], sp, 64);
                    W[i] += (lane >= sp) ? o : 0.0f;
                }
            }

            // column windows: S(ki) = P[ki+56] - P[ki-1]; write G (+mirror) into LDS
            const int kilo = di < 0 ? -di : 0;
            const int kihi = di > 0 ? 7 - di : 7;
            const int nki = kihi - kilo + 1;
            const int ki = kilo + lane;
            const int srcU = (kilo + lane + 56) & 63;
            const int srcL = (kilo + lane - 1) & 63;
            const bool wr = lane < nki;
            #pragma unroll
            for (int dj = 0; dj < 8; ++dj) {
                if (!(di < 0 && dj == 0)) {        // (di<0,dj=0) = mirror of (di>0,dj=0)
                    #pragma unroll
                    for (int st = 0; st < 8 - dj; ++st) {
                        const float Pv = W[woff(dj) + st];
                        const float su = __shfl(Pv, srcU, 64);
                        const float sl = __shfl(Pv, srcL, 64);
                        if (wr) {
                            const float S = su - ((ki > 0) ? sl : 0.0f);
                            const int m = ki * 8 + st, n = (ki + di) * 8 + (st + dj);
                            G[m * IMGS + n] = S;
                            G[n * IMGS + m] = S;
                        }
                    }
                }
            }
        }
    }
    __syncthreads();

    // ---- normalize + batched sort64 over lanes + ranked pool (wave wv: 16 columns) ----
    const int m = lane;
    const float invm = 1.0f / fmaxf(sqrtf(G[m * IMGS + m]), 1e-12f);
    const float sc = 1.0f / 3249.0f;
    const int n0 = wv * 16;
    float v[16];
    #pragma unroll
    for (int c = 0; c < 16; ++c) {
        float bn = __shfl(invm, n0 + c, 64);
        v[c] = G[m * IMGS + n0 + c] * invm * bn * sc;
    }
    #pragma unroll
    for (int kk = 2; kk <= 64; kk <<= 1) {
        #pragma unroll
        for (int j = kk >> 1; j > 0; j >>= 1) {
            bool upper = (lane & j) != 0;
            bool dir0  = (lane & kk) == 0;
            bool keep_max = dir0 ^ upper;
            float o[16];
            #pragma unroll
            for (int c = 0; c < 16; ++c) o[c] = __shfl_xor(v[c], j, 64);
            #pragma unroll
            for (int c = 0; c < 16; ++c) v[c] = keep_max ? fmaxf(v[c], o[c]) : fminf(v[c], o[c]);
        }
    }
    int ridx = -1;
    if      (lane ==  1) ridx = 0; else if (lane ==  9) ridx = 1; else if (lane == 16) ridx = 2;
    else if (lane == 24) ridx = 3; else if (lane == 32) ridx = 4; else if (lane == 40) ridx = 5;
    else if (lane == 48) ridx = 6; else if (lane == 55) ridx = 7; else if (lane == 63) ridx = 8;
    if (ridx >= 0) {
        float* dst = xp + (size_t)bc * 576 + ridx * 64 + n0;
        #pragma unroll
        for (int k = 0; k < 4; ++k)
            *(float4*)&dst[k * 4] = make_float4(v[k*4], v[k*4+1], v[k*4+2], v[k*4+3]);
    }
}

// ---------------- k3a: stage-2 Gram, LDS-tiled GEMM 64x64 tiles, fused norms ----------
// grid = 8*81 (b x 9x9 tiles), block = 256, 4x4 acc/thread; writes 576-wide rows
__global__ __launch_bounds__(256) void k3a(const float* __restrict__ xp,
                                           float* __restrict__ c2) {
    __shared__ __align__(16) float As[64 * 68];
    __shared__ __align__(16) float Bs[64 * 68];
    __shared__ __align__(16) float ipv[64], iqv[64];
    const int t = threadIdx.x;
    const int b = blockIdx.x / 81;
    const int r = blockIdx.x % 81;
    const int pt = r / 9, qt = r % 9;
    const int p0 = pt * 64, q0 = qt * 64;
    const float4* xp4 = (const float4*)(xp + (size_t)b * 64 * 576);

    #pragma unroll
    for (int k = 0; k < 4; ++k) {
        int c = k * 16 + (t >> 4), j = t & 15;
        *(float4*)&As[c * 68 + j * 4] = xp4[c * 144 + (p0 >> 2) + j];
        *(float4*)&Bs[c * 68 + j * 4] = xp4[c * 144 + (q0 >> 2) + j];
    }
    __syncthreads();

    if (t < 64) {
        float s = 0.f;
        #pragma unroll
        for (int c = 0; c < 64; ++c) { float vv = As[c * 68 + t]; s = fmaf(vv, vv, s); }
        ipv[t] = 1.0f / fmaxf(sqrtf(s), 1e-12f);
    } else if (t < 128) {
        int u = t - 64; float s = 0.f;
        #pragma unroll
        for (int c = 0; c < 64; ++c) { float vv = Bs[c * 68 + u]; s = fmaf(vv, vv, s); }
        iqv[u] = 1.0f / fmaxf(sqrtf(s), 1e-12f);
    }
    __syncthreads();

    const int tp = t & 15, tq = t >> 4;
    float acc[4][4] = {};
    #pragma unroll
    for (int c = 0; c < 64; ++c) {
        float4 a4 = *(const float4*)&As[c * 68 + tp * 4];
        float4 b4 = *(const float4*)&Bs[c * 68 + tq * 4];
        acc[0][0] = fmaf(a4.x, b4.x, acc[0][0]); acc[0][1] = fmaf(a4.x, b4.y, acc[0][1]);
        acc[0][2] = fmaf(a4.x, b4.z, acc[0][2]); acc[0][3] = fmaf(a4.x, b4.w, acc[0][3]);
        acc[1][0] = fmaf(a4.y, b4.x, acc[1][0]); acc[1][1] = fmaf(a4.y, b4.y, acc[1][1]);
        acc[1][2] = fmaf(a4.y, b4.z, acc[1][2]); acc[1][3] = fmaf(a4.y, b4.w, acc[1][3]);
        acc[2][0] = fmaf(a4.z, b4.x, acc[2][0]); acc[2][1] = fmaf(a4.z, b4.y, acc[2][1]);
        acc[2][2] = fmaf(a4.z, b4.z, acc[2][2]); acc[2][3] = fmaf(a4.z, b4.w, acc[2][3]);
        acc[3][0] = fmaf(a4.w, b4.x, acc[3][0]); acc[3][1] = fmaf(a4.w, b4.y, acc[3][1]);
        acc[3][2] = fmaf(a4.w, b4.z, acc[3][2]); acc[3][3] = fmaf(a4.w, b4.w, acc[3][3]);
    }

    float4 ip4 = *(const float4*)&ipv[tp * 4];
    #pragma unroll
    for (int qq = 0; qq < 4; ++qq) {
        int q = q0 + tq * 4 + qq;
        float iqs = iqv[tq * 4 + qq] * 0.015625f;   // /64
        float4 o;
        o.x = acc[0][qq] * ip4.x * iqs;
        o.y = acc[1][qq] * ip4.y * iqs;
        o.z = acc[2][qq] * ip4.z * iqs;
        o.w = acc[3][qq] * ip4.w * iqs;
        *(float4*)&c2[((size_t)(b * 576 + q)) * 576 + p0 + tp * 4] = o;
    }
}

// ---------------- k3b: per-wave register bitonic sort1024 + coalesced ranked out -------
// grid = 1152 (4 columns per block, one per wave), block = 256
__global__ __launch_bounds__(256) void k3b(const float* __restrict__ c2,
                                           float* __restrict__ out) {
    __shared__ float rankbuf[115][4];
    const int t = threadIdx.x;
    const int wv = t >> 6, lane = t & 63;
    const int gw = blockIdx.x * 4 + wv;           // b*576 + q
    const int b = (blockIdx.x * 4) / 576, q0 = (blockIdx.x * 4) % 576;
    float v[16];
    if (lane < 36) {                              // 36*16 = 576 real elements
        const float4* row4 = (const float4*)(c2 + (size_t)gw * 576);
        #pragma unroll
        for (int k = 0; k < 4; ++k) {
            float4 f = row4[lane * 4 + k];
            v[k * 4 + 0] = f.x; v[k * 4 + 1] = f.y; v[k * 4 + 2] = f.z; v[k * 4 + 3] = f.w;
        }
    } else {
        #pragma unroll
        for (int r = 0; r < 16; ++r) v[r] = -FLT_MAX;   // virtual padding to 1024
    }

    #pragma unroll
    for (int kk = 2; kk <= 1024; kk <<= 1) {
        #pragma unroll
        for (int j = kk >> 1; j > 0; j >>= 1) {
            if (j >= 16) {
                const int jl = j >> 4;
                bool upper = (lane & jl) != 0;
                bool dir0  = (lane & (kk >> 4)) == 0;
                bool keep_max = dir0 ^ upper;
                float o[16];
                #pragma unroll
                for (int r = 0; r < 16; ++r) o[r] = __shfl_xor(v[r], jl, 64);
                #pragma unroll
                for (int r = 0; r < 16; ++r) v[r] = keep_max ? fmaxf(v[r], o[r]) : fminf(v[r], o[r]);
            } else {
                #pragma unroll
                for (int ra = 0; ra < 16; ++ra) {
                    if ((ra & j) == 0) {
                        const int rb = ra | j;
                        bool dir0 = (kk >= 16) ? ((lane & (kk >> 4)) == 0) : ((ra & kk) == 0);
                        float a = v[ra], bb = v[rb];
                        float mx = fmaxf(a, bb), mn = fminf(a, bb);
                        v[ra] = dir0 ? mx : mn;
                        v[rb] = dir0 ? mn : mx;
                    }
                }
            }
        }
    }

    // ranks = round(linspace(1,575,115)) == 1 + 5i + floor(2i/57) + (2i%57>=29)
    // stash ranked values in LDS, then write coalesced float4 rows
    #pragma unroll
    for (int r = 0; r < 16; ++r) {
        int pos = lane * 16 + r;
        int rr0 = (int)((float)pos * 0.1993f);
        #pragma unroll
        for (int dd = -1; dd <= 2; ++dd) {
            int cand = rr0 + dd;
            if (cand >= 0 && cand < 115) {
                int ti = 2 * cand;
                int rk = 1 + 5 * cand + ti / 57 + ((ti % 57) >= 29 ? 1 : 0);
                if (rk == pos) rankbuf[cand][wv] = v[r];
            }
        }
    }
    __syncthreads();
    if (t < 115) {
        float4 o = make_float4(rankbuf[t][0], rankbuf[t][1], rankbuf[t][2], rankbuf[t][3]);
        *(float4*)&out[(size_t)b * 115 * 576 + (size_t)t * 576 + q0] = o;
    }
}

extern "C" void kernel_launch(void* const* d_in, const int* in_sizes, int n_in,
                              void* d_out, int out_size, void* d_ws, size_t ws_size,
                              hipStream_t stream) {
    const float* x = (const float*)d_in[0];   // [8,64,64,64] fp32
    float* out = (float*)d_out;               // [8,115,24,24] fp32
    float* xp = (float*)d_ws;                 // [8,64,576] = 294912 floats
    float* c2 = xp + 294912;                  // [8,576,576] = 2,654,208 floats
    // ws use: (294912 + 2654208)*4 B ~= 11.8 MiB

    k1 <<<dim3(512),  dim3(256), 0, stream>>>(x, xp);
    k3a<<<dim3(648),  dim3(256), 0, stream>>>(xp, c2);
    k3b<<<dim3(1152), dim3(256), 0, stream>>>(c2, out);
}

// Round 7
// 121.596 us; speedup vs baseline: 1.6331x; 1.1612x over previous
//
#include <hip/hip_runtime.h>
#include <math.h>
#include <float.h>

// b=8, c=64, H=W=64, KS=8 -> P = 57*57 = 3249.
// Stage 1 per (b,c): G[m,n] = <patch_m, patch_n> over P; corr = G/(sqrt(diag)sqrt(diag)P);
//   sort 64 m per column n desc; ranks {1,9,16,24,32,40,48,55,63} -> xp[b,c,576].
// Stage 2 per b: corr2[p,q] = sum_c Xn[c,p]Xn[c,q]/64; sort 576 p per q desc; 115 ranks.
//
// R7: k1 pair-symmetric (wave d covers +d and -d from one row-pair read) with DPP scan;
//     G canonical upper-triangle only; k3a+k3b fused (B via scalar loads, sort in-block).

#define IMGS 65

// ---- DPP helpers (compile-time ctrl via templates; LDS-pipe-free cross-lane) ----
template<int CTRL, int RM>
__device__ __forceinline__ float dpp_add(float x) {
    int o = __builtin_amdgcn_update_dpp(0, __float_as_int(x), CTRL, RM, 0xf, true);
    return x + __int_as_float(o);
}
// inclusive wave64 prefix sum: row_shr 1/2/4/8, then bcast15 (rows 1,3), bcast31 (rows 2,3)
__device__ __forceinline__ float wscan_add(float x) {
    x = dpp_add<0x111, 0xf>(x);
    x = dpp_add<0x112, 0xf>(x);
    x = dpp_add<0x114, 0xf>(x);
    x = dpp_add<0x118, 0xf>(x);
    x = dpp_add<0x142, 0xa>(x);
    x = dpp_add<0x143, 0xc>(x);
    return x;
}
template<int CTRL>
__device__ __forceinline__ float dpp_perm(float x) {
    int o = __builtin_amdgcn_update_dpp(__float_as_int(x), __float_as_int(x), CTRL, 0xf, 0xf, false);
    return __int_as_float(o);
}
// xor-1 / xor-2 within quads
#define QP_XOR1 0xB1   // [1,0,3,2]
#define QP_XOR2 0x4E   // [2,3,0,1]

__host__ __device__ constexpr int offF(int dj) { return dj * (17 - dj) / 2; }       // 36 total
__host__ __device__ constexpr int offB(int dj) { return (dj - 1) * (16 - dj) / 2; } // 28 total

// ---------------- k1: fused stage-1, pair-symmetric, canonical-G ----------------
// grid = 512 (bc), block = 512 (8 waves; wave wv handles row-shift d = wv)
__global__ __launch_bounds__(512) void k1(const float* __restrict__ x,
                                          float* __restrict__ xp) {
    __shared__ float img[64 * IMGS];   // 16.6 KB
    __shared__ float G[64 * IMGS];     // canonical: G[m*65+n], m<=n

    const int t = threadIdx.x;
    const int bc = blockIdx.x;
    const float* src = x + (size_t)bc * 4096;

    #pragma unroll
    for (int k = 0; k < 2; ++k) {
        int i4 = t + k * 512;
        float4 v = ((const float4*)src)[i4];
        int fl = i4 * 4, row = fl >> 6, col = fl & 63;
        float* dd = &img[row * IMGS + col];
        dd[0] = v.x; dd[1] = v.y; dd[2] = v.z; dd[3] = v.w;
    }
    __syncthreads();

    const int wv = t >> 6, lane = t & 63;
    const int d = wv;                            // 0..7
    const int a = lane;
    const bool av = (a + d <= 63);
    const int a1 = min(a + d, 63);
    const float* r0 = &img[a * IMGS];
    const float* r1 = &img[a1 * IMGS];

    // ---- FMA phase: wf[k]=sum r0[u]*r1[u+k], wb[k]=sum r1[u]*r0[u+k]  (u=0..56) ----
    float wf[8] = {0,0,0,0,0,0,0,0}, wb[8] = {0,0,0,0,0,0,0,0};
    float sf[8], sb[8], hf[7], hb[7];
    #pragma unroll
    for (int k = 0; k < 7; ++k) { sf[k] = r1[k]; sb[k] = r0[k]; hf[k] = sf[k]; hb[k] = sb[k]; }
    #pragma unroll
    for (int c = 0; c < 7; ++c) {
        #pragma unroll
        for (int j = 0; j < 8; ++j) {
            const int u = c * 8 + j;
            sf[(j + 7) & 7] = r1[u + 7];
            sb[(j + 7) & 7] = r0[u + 7];
            const float f0 = sb[j & 7];          // r0[u]
            const float g0 = sf[j & 7];          // r1[u]
            #pragma unroll
            for (int k = 0; k < 8; ++k) wf[k] = fmaf(f0, sf[(j + k) & 7], wf[k]);
            #pragma unroll
            for (int k = 1; k < 8; ++k) wb[k] = fmaf(g0, sb[(j + k) & 7], wb[k]);
        }
    }
    {   // u = 56 (j-pattern 0)
        sf[7] = r1[63]; sb[7] = r0[63];
        const float f0 = sb[0], g0 = sf[0];
        #pragma unroll
        for (int k = 0; k < 8; ++k) wf[k] = fmaf(f0, sf[k], wf[k]);
        #pragma unroll
        for (int k = 1; k < 8; ++k) wb[k] = fmaf(g0, sb[k], wb[k]);
    }
    // now sf[k] = r1[56+k], sb[k] = r0[56+k]  (tails); hf/hb = heads

    // ---- slide over st (all indices compile-time) ----
    float Wf[36], Wb[28];
    #pragma unroll
    for (int dj = 0; dj < 8; ++dj) {
        float a0 = wf[dj];
        Wf[offF(dj)] = a0;
        #pragma unroll
        for (int st = 1; st < 8 - dj; ++st) {
            a0 += sb[st] * sf[st + dj] - hb[st - 1] * hf[st - 1 + dj];
            Wf[offF(dj) + st] = a0;
        }
    }
    #pragma unroll
    for (int dj = 1; dj < 8; ++dj) {
        float a0 = wb[dj];
        Wb[offB(dj)] = a0;
        #pragma unroll
        for (int st = 1; st < 8 - dj; ++st) {
            a0 += sf[st] * sb[st + dj] - hf[st - 1] * hb[st - 1 + dj];
            Wb[offB(dj) + st] = a0;
        }
    }

    // ---- mask invalid rows, DPP prefix-scan over lanes (rows a) ----
    const float msk = av ? 1.0f : 0.0f;
    #pragma unroll
    for (int i = 0; i < 36; ++i) Wf[i] = wscan_add(Wf[i] * msk);
    if (d > 0) {
        #pragma unroll
        for (int i = 0; i < 28; ++i) Wb[i] = wscan_add(Wb[i] * msk);
    }

    // ---- extract: S(ki) on lane ki+56 = P[lane] - P[lane-57]; write canonical G ----
    const bool wr = (lane >= 56) && (lane <= 63 - d);
    const int ki = lane - 56;
    #pragma unroll
    for (int dj = 0; dj < 8; ++dj) {
        #pragma unroll
        for (int st = 0; st < 8 - dj; ++st) {
            {
                float P = Wf[offF(dj) + st];
                float sl = __shfl_up(P, 57, 64);
                float S = P - (lane >= 57 ? sl : 0.0f);
                if (wr) G[(ki * 8 + st) * IMGS + ((ki + d) * 8 + st + dj)] = S;
            }
            if (d > 0 && dj > 0) {
                float P = Wb[offB(dj) + st];
                float sl = __shfl_up(P, 57, 64);
                float S = P - (lane >= 57 ? sl : 0.0f);
                if (wr) G[(ki * 8 + st + dj) * IMGS + ((ki + d) * 8 + st)] = S;
            }
        }
    }
    __syncthreads();

    // ---- normalize + batched sort64 (wave wv: columns wv*8..wv*8+7) ----
    const int m = lane;
    const float invm = 1.0f / fmaxf(sqrtf(G[m * 66]), 1e-12f);
    const float sc = 1.0f / 3249.0f;
    const int c0 = wv * 8;
    float v[8];
    #pragma unroll
    for (int cc = 0; cc < 8; ++cc) {
        const int col = c0 + cc;
        const int addr = (m <= col) ? m * IMGS + col : col * IMGS + m;   // symmetric read
        const float invc = __shfl(invm, col, 64);
        v[cc] = G[addr] * invm * invc * sc;
    }
    #pragma unroll
    for (int kk = 2; kk <= 64; kk <<= 1) {
        #pragma unroll
        for (int j = kk >> 1; j > 0; j >>= 1) {
            const bool upper = (lane & j) != 0;
            const bool dir0  = (lane & kk) == 0;
            const bool keep_max = dir0 ^ upper;
            float o[8];
            #pragma unroll
            for (int cc = 0; cc < 8; ++cc) {
                if (j == 1)      o[cc] = dpp_perm<QP_XOR1>(v[cc]);
                else if (j == 2) o[cc] = dpp_perm<QP_XOR2>(v[cc]);
                else             o[cc] = __shfl_xor(v[cc], j, 64);
            }
            #pragma unroll
            for (int cc = 0; cc < 8; ++cc)
                v[cc] = keep_max ? fmaxf(v[cc], o[cc]) : fminf(v[cc], o[cc]);
        }
    }
    // ranks2 = {1,9,16,24,32,40,48,55,63}
    int ridx = -1;
    if      (lane ==  1) ridx = 0; else if (lane ==  9) ridx = 1; else if (lane == 16) ridx = 2;
    else if (lane == 24) ridx = 3; else if (lane == 32) ridx = 4; else if (lane == 40) ridx = 5;
    else if (lane == 48) ridx = 6; else if (lane == 55) ridx = 7; else if (lane == 63) ridx = 8;
    if (ridx >= 0) {
        float* dst = xp + (size_t)bc * 576 + ridx * 64 + c0;
        *(float4*)&dst[0] = make_float4(v[0], v[1], v[2], v[3]);
        *(float4*)&dst[4] = make_float4(v[4], v[5], v[6], v[7]);
    }
}

// ---------------- k3: fused stage-2 (Gram columns + norms + sort + ranks) ----------------
// grid = 8*64 (b x q-group of 9), block = 576 (9 waves; wave sorts column q0+wv)
__global__ __launch_bounds__(576) void k3(const float* __restrict__ xp,
                                          float* __restrict__ out) {
    __shared__ __align__(16) float sbuf[9 * 580];   // raw corr columns, stride 580 (16B-aligned)
    __shared__ __align__(16) float ipL[576];        // per-p inverse channel norms
    __shared__ float rankbuf[115 * 12];
    const int t = threadIdx.x;
    const int b = blockIdx.x >> 6, qg = blockIdx.x & 63;
    const int q0 = qg * 9;
    const float* __restrict__ xb = xp + (size_t)b * 36864;

    // ---- phase 1: thread p computes raw corr2 col entries for 9 q's + own norm ----
    {
        const int p = t;
        float acc[9] = {0,0,0,0,0,0,0,0,0};
        float sd = 0.f;
        #pragma unroll 8
        for (int c = 0; c < 64; ++c) {
            const float xv = xb[c * 576 + p];                  // coalesced vector load
            sd = fmaf(xv, xv, sd);
            #pragma unroll
            for (int qq = 0; qq < 9; ++qq)
                acc[qq] = fmaf(xv, xb[c * 576 + q0 + qq], acc[qq]);  // uniform -> s_load
        }
        ipL[p] = 1.0f / fmaxf(sqrtf(sd), 1e-12f);
        #pragma unroll
        for (int qq = 0; qq < 9; ++qq) sbuf[qq * 580 + p] = acc[qq];
    }
    __syncthreads();

    // ---- phase 2: wave wv sorts column q = q0+wv (1024-pad register bitonic) ----
    const int wv = t >> 6, lane = t & 63;
    float v[16];
    {
        const float ipq = ipL[q0 + wv] * 0.015625f;   // /64
        const float* sb2 = &sbuf[wv * 580];
        if (lane < 36) {
            #pragma unroll
            for (int k2 = 0; k2 < 4; ++k2) {
                float4 f   = *(const float4*)&sb2[lane * 16 + k2 * 4];
                float4 ip4 = *(const float4*)&ipL[lane * 16 + k2 * 4];
                v[k2 * 4 + 0] = f.x * ip4.x * ipq;
                v[k2 * 4 + 1] = f.y * ip4.y * ipq;
                v[k2 * 4 + 2] = f.z * ip4.z * ipq;
                v[k2 * 4 + 3] = f.w * ip4.w * ipq;
            }
        } else {
            #pragma unroll
            for (int r = 0; r < 16; ++r) v[r] = -FLT_MAX;
        }
    }

    #pragma unroll
    for (int kk = 2; kk <= 1024; kk <<= 1) {
        #pragma unroll
        for (int j = kk >> 1; j > 0; j >>= 1) {
            if (j >= 16) {
                const int jl = j >> 4;
                const bool upper = (lane & jl) != 0;
                const bool dir0  = (lane & (kk >> 4)) == 0;
                const bool keep_max = dir0 ^ upper;
                float o[16];
                #pragma unroll
                for (int r = 0; r < 16; ++r) {
                    if (jl == 1)      o[r] = dpp_perm<QP_XOR1>(v[r]);
                    else if (jl == 2) o[r] = dpp_perm<QP_XOR2>(v[r]);
                    else              o[r] = __shfl_xor(v[r], jl, 64);
                }
                #pragma unroll
                for (int r = 0; r < 16; ++r)
                    v[r] = keep_max ? fmaxf(v[r], o[r]) : fminf(v[r], o[r]);
            } else {
                #pragma unroll
                for (int ra = 0; ra < 16; ++ra) {
                    if ((ra & j) == 0) {
                        const int rb = ra | j;
                        const bool dir0 = (kk >= 16) ? ((lane & (kk >> 4)) == 0) : ((ra & kk) == 0);
                        float aa = v[ra], bb = v[rb];
                        float mx = fmaxf(aa, bb), mn = fminf(aa, bb);
                        v[ra] = dir0 ? mx : mn;
                        v[rb] = dir0 ? mn : mx;
                    }
                }
            }
        }
    }

    // ranks = round(linspace(1,575,115)) == 1 + 5i + floor(2i/57) + (2i%57>=29)
    #pragma unroll
    for (int r = 0; r < 16; ++r) {
        const int pos = lane * 16 + r;
        const int rr0 = (int)((float)pos * 0.1993f);
        #pragma unroll
        for (int dd = -1; dd <= 2; ++dd) {
            const int cand = rr0 + dd;
            if (cand >= 0 && cand < 115) {
                const int ti = 2 * cand;
                const int rk = 1 + 5 * cand + ti / 57 + ((ti % 57) >= 29 ? 1 : 0);
                if (rk == pos) rankbuf[cand * 12 + wv] = v[r];
            }
        }
    }
    __syncthreads();
    for (int i = t; i < 115 * 9; i += 576) {
        const int rr = i / 9, qq = i - rr * 9;
        out[(size_t)b * 66240 + rr * 576 + q0 + qq] = rankbuf[rr * 12 + qq];
    }
}

extern "C" void kernel_launch(void* const* d_in, const int* in_sizes, int n_in,
                              void* d_out, int out_size, void* d_ws, size_t ws_size,
                              hipStream_t stream) {
    const float* x = (const float*)d_in[0];   // [8,64,64,64] fp32
    float* out = (float*)d_out;               // [8,115,24,24] fp32
    float* xp = (float*)d_ws;                 // [8,64,576] = 294912 floats (~1.2 MB)

    k1<<<dim3(512), dim3(512), 0, stream>>>(x, xp);
    k3<<<dim3(512), dim3(576), 0, stream>>>(xp, out);
}